// Round 1
// 118.640 us; speedup vs baseline: 1.0574x; 1.0574x over previous
//
#include <hip/hip_runtime.h>
#include <hip/hip_bf16.h>
#include <math.h>

#define BATCH 8
#define NPTS 4096
#define CH 128
#define CTG 4                         // column groups per batch-row-tile
#define CHUNK 64                      // columns staged per pipeline step
#define NCHUNK (NPTS / (CTG * CHUNK)) // 16 chunks per block

// exp(s/TEMP) = 2^(s * 10 * log2(e)). sqrt(10/ln2) is folded into the
// normalize scale so the GEMM accumulator is already the exp2 argument.
#define SQRT_TEMP_LOG2E 3.79828256f   // sqrt(14.4269504089)

typedef __attribute__((ext_vector_type(4))) float f32x4;
typedef __attribute__((ext_vector_type(4))) int   i32x4;
typedef __attribute__((ext_vector_type(8))) short bf16x8;

typedef __attribute__((address_space(3))) unsigned int lds_uint;
typedef __attribute__((address_space(1))) const unsigned int gbl_uint;

__device__ __forceinline__ void load_lds16(const void* g, const void* l) {
    __builtin_amdgcn_global_load_lds((gbl_uint*)g, (lds_uint*)l, 16, 0, 0);
}

__device__ __forceinline__ float fast_exp2(float x) {
    return __builtin_amdgcn_exp2f(x);
}

// ---------------------------------------------------------------------------
// Kernel 1: one-pass L2-normalize (4 threads/point, 32 ch each in registers),
// zero pos/neg and the output scalar.
// ---------------------------------------------------------------------------
__global__ __launch_bounds__(256) void normalize_kernel(
    const float* __restrict__ f, __hip_bfloat16* __restrict__ vn,
    float* __restrict__ pos, float* __restrict__ neg, float* __restrict__ out)
{
    int idx = blockIdx.x * 256 + threadIdx.x;   // 0 .. 131071
    int point = idx >> 2, q = idx & 3;
    int b = point >> 12, n = point & (NPTS - 1);
    const float* base = f + (size_t)b * CH * NPTS + (size_t)(q * 32) * NPTS + n;

    float x[32];
    float ss = 0.0f;
    #pragma unroll
    for (int c = 0; c < 32; c++) {
        x[c] = base[(size_t)c * NPTS];
        ss += x[c] * x[c];
    }
    ss += __shfl_xor(ss, 1);
    ss += __shfl_xor(ss, 2);    // 4 lanes of one point share ss
    float scale = SQRT_TEMP_LOG2E / fmaxf(sqrtf(ss), 1e-12f);

    __hip_bfloat16* outp = vn + (size_t)point * CH + q * 32;
    #pragma unroll
    for (int c0 = 0; c0 < 32; c0 += 8) {
        union { __hip_bfloat16 h[8]; uint4 u; } pk;
        #pragma unroll
        for (int j = 0; j < 8; j++)
            pk.h[j] = __float2bfloat16(x[c0 + j] * scale);
        *((uint4*)(outp + c0)) = pk.u;
    }
    if (q == 0) pos[point] = 0.0f;
    else if (q == 1) neg[point] = 0.0f;
    if (idx == 0) out[0] = 0.0f;
}

// ---------------------------------------------------------------------------
// Kernel 2: persistent column-strip GEMM. Each block owns rows rt*128..+128
// and a 1024-col strip (ctg), processed as 16 chunks of 64 cols with
// double-buffered global_load_lds staging and COUNTED vmcnt (never 0 in the
// loop) + raw s_barrier — the T3/T4 pipeline. A-fragments and the row
// pos/tot accumulators live in registers for the whole strip, so the old
// per-tile shfl+atomic tail (2.1M atomics) collapses to once per block
// (262K atomics).
//
// Swapped operands: mfma(bfrag, afrag, acc) puts S-row on lane&15 (in-lane
// reduction) and S-col on quad*4+reg. acc[mi][ni] element (lane,r) =
//   S[row0 + w*32 + mi*16 + lane15][colbase + chunk*64 + ni*16 + quad*4 + r]
//
// LDS: 2*16KB staging + 4KB labels = 36KB -> 4 blocks/CU.
// launch_bounds(256,4): 128-reg cap (~110 used: 32 afrag + 32 acc + misc).
// WRITE_SIZE is the spill tripwire (R4: 178 MB explosion).
// ---------------------------------------------------------------------------
__global__ __launch_bounds__(256, 4) void tile_kernel(
    const __hip_bfloat16* __restrict__ vn, const int* __restrict__ labels,
    float* __restrict__ pos, float* __restrict__ neg)
{
    __shared__ short lB[2][CHUNK * CH];   // 2 x 16 KB double buffer
    __shared__ int labL[NPTS / CTG];      // 1024 column labels of this strip

    const int ctg = blockIdx.x, rt = blockIdx.y, b = blockIdx.z;
    const int tid = threadIdx.x;
    const int w = tid >> 6, lane = tid & 63;
    const int lane15 = lane & 15, quad = lane >> 4;

    const int row0 = rt * 128;
    const int colbase = ctg * (NPTS / CTG);
    const __hip_bfloat16* vb = vn + (size_t)b * NPTS * CH;
    const int* labb = labels + b * NPTS;

    // Stage one 64-col chunk -> LDS buffer. XOR chunk swizzle at the global
    // source (LDS dest order is HW-fixed: wave-uniform base + lane*16B;
    // lane l -> row base+quad, chunk lane15). 4 waves x 4 iters x 4 rows.
    // Proven 0 bank conflicts (R1..R8 swizzle, unchanged).
    auto STAGE = [&](int buf, int chunk) {
        const __hip_bfloat16* Bb = vb + (size_t)(colbase + chunk * CHUNK) * CH;
        #pragma unroll
        for (int i = 0; i < 4; i++) {
            int ldsrow = w * 16 + i * 4;            // wave-uniform
            int r = ldsrow + quad;                  // row this lane feeds
            int g = lane15 ^ (r & 15);              // swizzled global chunk
            load_lds16(Bb + (size_t)r * CH + g * 8, &lB[buf][ldsrow * CH]);
        }
    };

    // ---- prologue: labels -> LDS (1 op), chunk 0 -> buf 0 (4 ops), A-frags
    // (8 loads) + row labels (2 loads). All drained by body0's vmcnt(4).
    load_lds16(labb + colbase + w * 256 + lane * 4, &labL[w * 256]);
    STAGE(0, 0);

    bf16x8 afrag[2][4];
    int lr[2];
    #pragma unroll
    for (int mi = 0; mi < 2; mi++) {
        const int row_l = w * 32 + mi * 16 + lane15;
        const __hip_bfloat16* Arow = vb + (size_t)(row0 + row_l) * CH;
        #pragma unroll
        for (int ks = 0; ks < 4; ks++)
            afrag[mi][ks] = *(const bf16x8*)(Arow + (ks * 4 + quad) * 8);
        lr[mi] = labb[row0 + row_l];
    }

    float pacc[2] = {0.0f, 0.0f}, tacc[2] = {0.0f, 0.0f};

    // ---- one pipeline step. Order per step:
    //   stage(next chunk)            -> +4 vmcnt ops in flight
    //   s_waitcnt vmcnt(4)           -> previous chunk's 4 loads retired
    //   s_barrier                    -> cur buffer valid for all waves
    //   ds_read + MFMA (setprio 1)   -> consume cur
    //   s_barrier                    -> cur free for overwrite next step
    //   epilogue (exp2/accumulate)   -> overlaps other waves' next stage
    auto BODY = [&](int chunk, int buf) {
        STAGE(buf ^ 1, (chunk + 1) & (NCHUNK - 1));  // wrap: last stage is dead
        asm volatile("s_waitcnt vmcnt(4)" ::: "memory");
        __builtin_amdgcn_s_barrier();

        f32x4 acc[2][4] = {};
        __builtin_amdgcn_s_setprio(1);
        #pragma unroll
        for (int ks = 0; ks < 4; ks++) {
            const int koff = ((ks * 4 + quad) ^ lane15) << 3;   // shorts
            #pragma unroll
            for (int ni = 0; ni < 4; ni++) {
                bf16x8 bf = *(const bf16x8*)&lB[buf][(ni * 16 + lane15) * CH + koff];
                acc[0][ni] = __builtin_amdgcn_mfma_f32_16x16x32_bf16(
                    bf, afrag[0][ks], acc[0][ni], 0, 0, 0);
                acc[1][ni] = __builtin_amdgcn_mfma_f32_16x16x32_bf16(
                    bf, afrag[1][ks], acc[1][ni], 0, 0, 0);
            }
        }
        __builtin_amdgcn_s_setprio(0);
        __builtin_amdgcn_s_barrier();   // all ds_reads of buf retired (lgkm
                                        // waits precede the MFMAs above)

        #pragma unroll
        for (int ni = 0; ni < 4; ni++) {
            const i32x4 lc = *(const i32x4*)&labL[chunk * CHUNK + ni * 16 + quad * 4];
            const int colblk = colbase + chunk * CHUNK + ni * 16;
            #pragma unroll
            for (int mi = 0; mi < 2; mi++) {
                const bool dblk = (colblk == row0 + w * 32 + mi * 16); // wave-unif
                if (dblk) {
                    #pragma unroll
                    for (int r = 0; r < 4; r++) {
                        float e = fast_exp2(acc[mi][ni][r]);
                        if (lane15 == quad * 4 + r) e = 0.0f;   // diagonal
                        tacc[mi] += e;
                        pacc[mi] += (lc[r] == lr[mi]) ? e : 0.0f;
                    }
                } else {
                    #pragma unroll
                    for (int r = 0; r < 4; r++) {
                        float e = fast_exp2(acc[mi][ni][r]);
                        tacc[mi] += e;
                        pacc[mi] += (lc[r] == lr[mi]) ? e : 0.0f;
                    }
                }
            }
        }
    };

    #pragma unroll 1
    for (int c2 = 0; c2 < NCHUNK; c2 += 2) {
        BODY(c2, 0);
        BODY(c2 + 1, 1);
    }

    // ---- strip done: fold quads, one pos/neg atomic pair per row.
    #pragma unroll
    for (int mi = 0; mi < 2; mi++) {
        float p = pacc[mi], tt = tacc[mi];
        p  += __shfl_xor(p, 16);   p  += __shfl_xor(p, 32);
        tt += __shfl_xor(tt, 16);  tt += __shfl_xor(tt, 32);
        if (lane < 16) {
            const int row_l = w * 32 + mi * 16 + lane15;
            atomicAdd(&pos[b * NPTS + row0 + row_l], p);
            atomicAdd(&neg[b * NPTS + row0 + row_l], tt - p);
        }
    }
}

// ---------------------------------------------------------------------------
// Kernel 3: mean of log((p+n)/p) over 32768 rows. 32 blocks x 256 threads
// (the old single-block version was one-CU latency-bound); out zeroed by
// normalize_kernel, stream order makes the atomics safe.
// ---------------------------------------------------------------------------
__global__ __launch_bounds__(256) void finalize_kernel(
    const float* __restrict__ pos, const float* __restrict__ neg,
    float* __restrict__ out)
{
    int base = blockIdx.x * 1024 + threadIdx.x;
    float acc = 0.0f;
    #pragma unroll
    for (int k = 0; k < 4; k++) {
        int i = base + k * 256;
        float p = pos[i];
        float t = p + neg[i];
        acc += __logf(t / p);   // == -log(p / (p+n))
    }
    #pragma unroll
    for (int off = 32; off; off >>= 1) acc += __shfl_down(acc, off);
    __shared__ float red[4];
    if ((threadIdx.x & 63) == 0) red[threadIdx.x >> 6] = acc;
    __syncthreads();
    if (threadIdx.x == 0) {
        float v = red[0] + red[1] + red[2] + red[3];
        atomicAdd(out, v * (1.0f / (BATCH * NPTS)));
    }
}

extern "C" void kernel_launch(void* const* d_in, const int* in_sizes, int n_in,
                              void* d_out, int out_size, void* d_ws, size_t ws_size,
                              hipStream_t stream)
{
    const float* features = (const float*)d_in[0];
    const int*   labels   = (const int*)d_in[1];
    float*       out      = (float*)d_out;

    // Workspace: vn bf16 [8][4096][128] = 8 MB, then pos/neg fp32.
    __hip_bfloat16* vn = (__hip_bfloat16*)d_ws;
    float* pos = (float*)((char*)d_ws + (size_t)BATCH * NPTS * CH * sizeof(__hip_bfloat16));
    float* neg = pos + BATCH * NPTS;

    hipLaunchKernelGGL(normalize_kernel, dim3(BATCH * NPTS * 4 / 256), dim3(256), 0, stream,
                       features, vn, pos, neg, out);
    // Persistent strip grid: 4 ctg x 32 rt x 8 batches = 1024 blocks = 4/CU.
    hipLaunchKernelGGL(tile_kernel, dim3(CTG, 32, BATCH), dim3(256), 0, stream,
                       vn, labels, pos, neg);
    hipLaunchKernelGGL(finalize_kernel, dim3(32), dim3(256), 0, stream, pos, neg, out);
}

// Round 2
// 112.826 us; speedup vs baseline: 1.1119x; 1.0515x over previous
//
#include <hip/hip_runtime.h>
#include <hip/hip_bf16.h>
#include <math.h>

#define BATCH 8
#define NPTS 4096
#define CH 128
#define CTG 4                         // column strips per batch-row-tile
#define CHUNK 32                      // columns staged per pipeline step
#define NCHUNK (NPTS / (CTG * CHUNK)) // 32 chunks per block
#define NBUF 4                        // 3-deep prefetch ring

// exp(s/TEMP) = 2^(s * 10 * log2(e)). sqrt(10/ln2) is folded into the
// normalize scale so the GEMM accumulator is already the exp2 argument.
#define SQRT_TEMP_LOG2E 3.79828256f   // sqrt(14.4269504089)

typedef __attribute__((ext_vector_type(4))) float f32x4;
typedef __attribute__((ext_vector_type(4))) int   i32x4;
typedef __attribute__((ext_vector_type(8))) short bf16x8;

typedef __attribute__((address_space(3))) unsigned int lds_uint;
typedef __attribute__((address_space(1))) const unsigned int gbl_uint;

__device__ __forceinline__ void load_lds16(const void* g, const void* l) {
    __builtin_amdgcn_global_load_lds((gbl_uint*)g, (lds_uint*)l, 16, 0, 0);
}

__device__ __forceinline__ float fast_exp2(float x) {
    return __builtin_amdgcn_exp2f(x);
}

// ---------------------------------------------------------------------------
// Kernel 1: one-pass L2-normalize (4 threads/point, 32 ch each in registers),
// zero pos/neg and the output scalar.
// ---------------------------------------------------------------------------
__global__ __launch_bounds__(256) void normalize_kernel(
    const float* __restrict__ f, __hip_bfloat16* __restrict__ vn,
    float* __restrict__ pos, float* __restrict__ neg, float* __restrict__ out)
{
    int idx = blockIdx.x * 256 + threadIdx.x;   // 0 .. 131071
    int point = idx >> 2, q = idx & 3;
    int b = point >> 12, n = point & (NPTS - 1);
    const float* base = f + (size_t)b * CH * NPTS + (size_t)(q * 32) * NPTS + n;

    float x[32];
    float ss = 0.0f;
    #pragma unroll
    for (int c = 0; c < 32; c++) {
        x[c] = base[(size_t)c * NPTS];
        ss += x[c] * x[c];
    }
    ss += __shfl_xor(ss, 1);
    ss += __shfl_xor(ss, 2);    // 4 lanes of one point share ss
    float scale = SQRT_TEMP_LOG2E / fmaxf(sqrtf(ss), 1e-12f);

    __hip_bfloat16* outp = vn + (size_t)point * CH + q * 32;
    #pragma unroll
    for (int c0 = 0; c0 < 32; c0 += 8) {
        union { __hip_bfloat16 h[8]; uint4 u; } pk;
        #pragma unroll
        for (int j = 0; j < 8; j++)
            pk.h[j] = __float2bfloat16(x[c0 + j] * scale);
        *((uint4*)(outp + c0)) = pk.u;
    }
    if (q == 0) pos[point] = 0.0f;
    else if (q == 1) neg[point] = 0.0f;
    if (idx == 0) out[0] = 0.0f;
}

// ---------------------------------------------------------------------------
// Kernel 2: persistent column-strip GEMM, 3-DEEP prefetch ring.
//
// R1 post-mortem: 1-deep prefetch (2 buffers, CHUNK=64) left ~26 us where
// both MFMA and VALU pipes idle — FETCH_SIZE shows ~10% of staged bytes
// come from HBM (~900 cy), but one body is only ~550 cy, so vmcnt stalled
// every HBM-missing chunk. Fix: CHUNK=32, NBUF=4, stage chunk c+3 in body
// c (~1400 cy in flight > 900 cy HBM latency). LDS = 4x8KB + 4KB labels =
// 36 KB — identical budget, still 4 blocks/CU.
//
// vmcnt(6) is exact in steady state: after staging c+3, this wave's
// outstanding vm ops = chunks c+1,c+2,c+3 = 6 loads, so vmcnt(6) retires
// precisely chunk c. Prologue issues labels -> afrag -> stages 0..2; body
// 0's vmcnt(6) keeps only the newest 6 ops, which guarantees chunk 0 +
// labels retired (afrag covered by compiler's own waits before first use).
// NO other vm ops may appear inside the loop (spill tripwire: WRITE_SIZE).
//
// Barrier placement per body: [STAGE(c+3) | vmcnt(6) | bar | MFMA | bar |
// epilogue]. Read-validity: bar after vmcnt => every wave's chunk-c loads
// retired before any wave reads buf c. Overwrite-safety: STAGE at body c
// targets buf (c+3)&3 = (c-1)&3, whose last readers ran in body c-1 before
// that body's second barrier.
//
// Swapped operands: mfma(bfrag, afrag, acc) puts S-row on lane&15 (in-lane
// reduction) and S-col on quad*4+reg. acc[mi][ni] element (lane,r) =
//   S[row0 + w*32 + mi*16 + lane15][colbase + chunk*32 + ni*16 + quad*4 + r]
// ---------------------------------------------------------------------------
__global__ __launch_bounds__(256, 4) void tile_kernel(
    const __hip_bfloat16* __restrict__ vn, const int* __restrict__ labels,
    float* __restrict__ pos, float* __restrict__ neg)
{
    __shared__ short lB[NBUF][CHUNK * CH];   // 4 x 8 KB ring
    __shared__ int labL[NPTS / CTG];         // 1024 column labels of strip

    const int ctg = blockIdx.x, rt = blockIdx.y, b = blockIdx.z;
    const int tid = threadIdx.x;
    const int w = tid >> 6, lane = tid & 63;
    const int lane15 = lane & 15, quad = lane >> 4;

    const int row0 = rt * 128;
    const int colbase = ctg * (NPTS / CTG);
    const __hip_bfloat16* vb = vn + (size_t)b * NPTS * CH;
    const int* labb = labels + b * NPTS;

    // Stage one 32-col chunk -> ring buffer. XOR chunk swizzle at the global
    // source (LDS dest order is HW-fixed: wave-uniform base + lane*16B;
    // lane l -> row base+quad, chunk lane15). 4 waves x 2 iters x 4 rows.
    // Proven 0 bank conflicts (R1..R8 swizzle, unchanged math).
    auto STAGE = [&](int buf, int chunk) {
        const __hip_bfloat16* Bb = vb + (size_t)(colbase + chunk * CHUNK) * CH;
        #pragma unroll
        for (int i = 0; i < 2; i++) {
            int ldsrow = w * 8 + i * 4;             // wave-uniform
            int r = ldsrow + quad;                  // row this lane feeds
            int g = lane15 ^ (r & 15);              // swizzled global chunk
            load_lds16(Bb + (size_t)r * CH + g * 8, &lB[buf][ldsrow * CH]);
        }
    };

    // ---- prologue. Issue order matters for the vmcnt(6) accounting:
    // labels (1 op) -> afrag+lr (10 ops) -> stages 0,1,2 (6 ops).
    load_lds16(labb + colbase + w * 256 + lane * 4, &labL[w * 256]);

    bf16x8 afrag[2][4];
    int lr[2];
    #pragma unroll
    for (int mi = 0; mi < 2; mi++) {
        const int row_l = w * 32 + mi * 16 + lane15;
        const __hip_bfloat16* Arow = vb + (size_t)(row0 + row_l) * CH;
        #pragma unroll
        for (int ks = 0; ks < 4; ks++)
            afrag[mi][ks] = *(const bf16x8*)(Arow + (ks * 4 + quad) * 8);
        lr[mi] = labb[row0 + row_l];
    }

    STAGE(0, 0);
    STAGE(1, 1);
    STAGE(2, 2);

    float pacc[2] = {0.0f, 0.0f}, tacc[2] = {0.0f, 0.0f};

    auto BODY = [&](int chunk, int buf) {
        STAGE((buf + 3) & (NBUF - 1), (chunk + 3) & (NCHUNK - 1));
        asm volatile("s_waitcnt vmcnt(6)" ::: "memory");
        __builtin_amdgcn_s_barrier();

        f32x4 acc[2][2] = {};
        __builtin_amdgcn_s_setprio(1);
        #pragma unroll
        for (int ks = 0; ks < 4; ks++) {
            const int koff = ((ks * 4 + quad) ^ lane15) << 3;   // shorts
            #pragma unroll
            for (int ni = 0; ni < 2; ni++) {
                bf16x8 bf = *(const bf16x8*)&lB[buf][(ni * 16 + lane15) * CH + koff];
                acc[0][ni] = __builtin_amdgcn_mfma_f32_16x16x32_bf16(
                    bf, afrag[0][ks], acc[0][ni], 0, 0, 0);
                acc[1][ni] = __builtin_amdgcn_mfma_f32_16x16x32_bf16(
                    bf, afrag[1][ks], acc[1][ni], 0, 0, 0);
            }
        }
        __builtin_amdgcn_s_setprio(0);
        __builtin_amdgcn_s_barrier();   // last readers of buf done before it
                                        // is re-staged at body chunk+1

        // Epilogue on registers only — overlaps other waves' stage/MFMA.
        #pragma unroll
        for (int ni = 0; ni < 2; ni++) {
            const i32x4 lc = *(const i32x4*)&labL[chunk * CHUNK + ni * 16 + quad * 4];
            const int colblk = colbase + chunk * CHUNK + ni * 16;
            #pragma unroll
            for (int mi = 0; mi < 2; mi++) {
                const bool dblk = (colblk == row0 + w * 32 + mi * 16); // wave-unif
                if (dblk) {
                    #pragma unroll
                    for (int r = 0; r < 4; r++) {
                        float e = fast_exp2(acc[mi][ni][r]);
                        if (lane15 == quad * 4 + r) e = 0.0f;   // diagonal
                        tacc[mi] += e;
                        pacc[mi] += (lc[r] == lr[mi]) ? e : 0.0f;
                    }
                } else {
                    #pragma unroll
                    for (int r = 0; r < 4; r++) {
                        float e = fast_exp2(acc[mi][ni][r]);
                        tacc[mi] += e;
                        pacc[mi] += (lc[r] == lr[mi]) ? e : 0.0f;
                    }
                }
            }
        }
    };

    #pragma unroll 1
    for (int c4 = 0; c4 < NCHUNK; c4 += 4) {
        BODY(c4 + 0, 0);
        BODY(c4 + 1, 1);
        BODY(c4 + 2, 2);
        BODY(c4 + 3, 3);
    }

    // ---- strip done: fold quads, one pos/neg atomic pair per row.
    #pragma unroll
    for (int mi = 0; mi < 2; mi++) {
        float p = pacc[mi], tt = tacc[mi];
        p  += __shfl_xor(p, 16);   p  += __shfl_xor(p, 32);
        tt += __shfl_xor(tt, 16);  tt += __shfl_xor(tt, 32);
        if (lane < 16) {
            const int row_l = w * 32 + mi * 16 + lane15;
            atomicAdd(&pos[b * NPTS + row0 + row_l], p);
            atomicAdd(&neg[b * NPTS + row0 + row_l], tt - p);
        }
    }
}

// ---------------------------------------------------------------------------
// Kernel 3: mean of log((p+n)/p) over 32768 rows. 32 blocks x 256 threads;
// out zeroed by normalize_kernel, stream order makes the atomic safe.
// ---------------------------------------------------------------------------
__global__ __launch_bounds__(256) void finalize_kernel(
    const float* __restrict__ pos, const float* __restrict__ neg,
    float* __restrict__ out)
{
    int base = blockIdx.x * 1024 + threadIdx.x;
    float acc = 0.0f;
    #pragma unroll
    for (int k = 0; k < 4; k++) {
        int i = base + k * 256;
        float p = pos[i];
        float t = p + neg[i];
        acc += __logf(t / p);   // == -log(p / (p+n))
    }
    #pragma unroll
    for (int off = 32; off; off >>= 1) acc += __shfl_down(acc, off);
    __shared__ float red[4];
    if ((threadIdx.x & 63) == 0) red[threadIdx.x >> 6] = acc;
    __syncthreads();
    if (threadIdx.x == 0) {
        float v = red[0] + red[1] + red[2] + red[3];
        atomicAdd(out, v * (1.0f / (BATCH * NPTS)));
    }
}

extern "C" void kernel_launch(void* const* d_in, const int* in_sizes, int n_in,
                              void* d_out, int out_size, void* d_ws, size_t ws_size,
                              hipStream_t stream)
{
    const float* features = (const float*)d_in[0];
    const int*   labels   = (const int*)d_in[1];
    float*       out      = (float*)d_out;

    // Workspace: vn bf16 [8][4096][128] = 8 MB, then pos/neg fp32.
    __hip_bfloat16* vn = (__hip_bfloat16*)d_ws;
    float* pos = (float*)((char*)d_ws + (size_t)BATCH * NPTS * CH * sizeof(__hip_bfloat16));
    float* neg = pos + BATCH * NPTS;

    hipLaunchKernelGGL(normalize_kernel, dim3(BATCH * NPTS * 4 / 256), dim3(256), 0, stream,
                       features, vn, pos, neg, out);
    // Persistent strip grid: 4 ctg x 32 rt x 8 batches = 1024 blocks = 4/CU.
    hipLaunchKernelGGL(tile_kernel, dim3(CTG, 32, BATCH), dim3(256), 0, stream,
                       vn, labels, pos, neg);
    hipLaunchKernelGGL(finalize_kernel, dim3(32), dim3(256), 0, stream, pos, neg, out);
}